// Round 7
// baseline (261.297 us; speedup 1.0000x reference)
//
#include <hip/hip_runtime.h>
#include <stdint.h>

#define SEQ   4096
#define DIN   1024
#define NBLK  256
#define NITEMS 1024

typedef __attribute__((ext_vector_type(8))) short bf16x8;
typedef __attribute__((ext_vector_type(4))) float floatx4;
typedef __attribute__((ext_vector_type(4))) unsigned short ushortx4;

#if __has_builtin(__builtin_amdgcn_exp2f)
#define EXP2(x) __builtin_amdgcn_exp2f(x)
#else
#define EXP2(x) exp2f(x)
#endif

__device__ __forceinline__ unsigned short f2bf(float f) {
    union { float f; unsigned int u; } v; v.f = f;
    unsigned int u = v.u + 0x7fffu + ((v.u >> 16) & 1u);
    return (unsigned short)(u >> 16);
}
__device__ __forceinline__ float bf2f(unsigned short h) {
    union { unsigned int u; float f; } v; v.u = ((unsigned int)h) << 16;
    return v.f;
}
__device__ __forceinline__ float uasf(unsigned int u) {
    union { unsigned int u; float f; } v; v.u = u; return v.f;
}
__device__ __forceinline__ unsigned int fasu(float f) {
    union { float f; unsigned int u; } v; v.f = f; return v.u;
}
__device__ __forceinline__ float dpp_xor1(float x) {   // quad_perm [1,0,3,2]
    return uasf((unsigned)__builtin_amdgcn_mov_dpp((int)fasu(x), 0xB1, 0xF, 0xF, true));
}
__device__ __forceinline__ float dpp_xor2(float x) {   // quad_perm [2,3,0,1]
    return uasf((unsigned)__builtin_amdgcn_mov_dpp((int)fasu(x), 0x4E, 0xF, 0xF, true));
}

// device-scope soft grid barrier. Safe: capacity 2 blocks/CU (LDS 80 KB,
// VGPR<=128) => 512 resident slots >= 256 blocks, no deadlock.
// __syncthreads drains each wave's stores to L2 (vmcnt0 at barrier);
// tid0's threadfence (agent release: L2 writeback) + release-add publish;
// acquire spin invalidates reader caches.
__device__ __forceinline__ void gbar(unsigned int* c, int tid) {
    __syncthreads();
    if (tid == 0) {
        __threadfence();
        __hip_atomic_fetch_add(c, 1u, __ATOMIC_RELEASE, __HIP_MEMORY_SCOPE_AGENT);
        while (__hip_atomic_load(c, __ATOMIC_ACQUIRE, __HIP_MEMORY_SCOPE_AGENT) < NBLK)
            __builtin_amdgcn_s_sleep(1);
    }
    __syncthreads();
}

#define QSCALE 0.18033688011112042f

__launch_bounds__(512, 4)
__global__ void mega(const float* __restrict__ X, const float* __restrict__ Wq,
                     const float* __restrict__ Wk, const float* __restrict__ Wv,
                     unsigned short* __restrict__ WT, unsigned short* __restrict__ qb,
                     unsigned short* __restrict__ kb, unsigned short* __restrict__ vb,
                     unsigned short* __restrict__ opart, float* __restrict__ lpart,
                     unsigned int* cnt, float* __restrict__ out) {
    __shared__ __align__(16) char smem[81920];
    const int tid = threadIdx.x, bid = blockIdx.x;
    const int wave = tid >> 6, lane = tid & 63;
    const int quad = lane >> 4, l16 = lane & 15;

    // ================= phase 0: WT[mat*64+n][k] = bf16(W[k][n]) =============
    // write-coalesced; strided reads absorbed by L1/L2 (W is only 0.75 MB).
    for (int idx = bid * 512 + tid; idx < 196608; idx += 131072) {
        int k = idx & 1023, n = (idx >> 10) & 63, mat = idx >> 16;
        const float* W = (mat == 0) ? Wq : ((mat == 1) ? Wk : Wv);
        WT[idx] = f2bf(W[k * 64 + n]);
    }
    gbar(cnt + 0, tid);

    // ================= phase 1: projection (BM=64, dbuf reg-prefetch) =======
    {
        float*          X0 = (float*)smem;                       // 16 KB
        float*          X1 = (float*)(smem + 16384);             // 16 KB
        unsigned short* W0 = (unsigned short*)(smem + 32768);    // 24 KB
        unsigned short* W1 = (unsigned short*)(smem + 57344);    // 24 KB
        const int strip = wave >> 1, cg = wave & 1;
        const int row0 = bid * 64;
        const int m = strip * 16 + l16;

        floatx4 acc[6];
#pragma unroll
        for (int i = 0; i < 6; i++) acc[i] = (floatx4){0.f, 0.f, 0.f, 0.f};

        int xu[2], xr[2], xc[2], wu[3], wr[3], wc[3];
#pragma unroll
        for (int i = 0; i < 2; i++) {
            xu[i] = i * 512 + tid; xr[i] = xu[i] >> 4; xc[i] = (xu[i] & 15) ^ (xr[i] & 15);
        }
#pragma unroll
        for (int i = 0; i < 3; i++) {
            wu[i] = i * 512 + tid; wr[i] = wu[i] >> 3; wc[i] = (wu[i] & 7) ^ (wr[i] & 7);
        }
        floatx4 xpre[2], wpre[3];
        auto issue = [&](int k0) {
#pragma unroll
            for (int i = 0; i < 2; i++)
                xpre[i] = *(const floatx4*)(X + (size_t)(row0 + xr[i]) * DIN + k0 + xc[i] * 4);
#pragma unroll
            for (int i = 0; i < 3; i++)
                wpre[i] = *(const floatx4*)(WT + (size_t)wr[i] * 1024 + k0 + wc[i] * 8);
        };

        issue(0);
        for (int kc = 0; kc < 16; kc++) {
            float*          Xd = (kc & 1) ? X1 : X0;
            unsigned short* Wd = (kc & 1) ? W1 : W0;
#pragma unroll
            for (int i = 0; i < 2; i++) *(floatx4*)&Xd[xu[i] * 4] = xpre[i];
#pragma unroll
            for (int i = 0; i < 3; i++) *(floatx4*)&Wd[wu[i] * 8] = wpre[i];
            if (kc < 15) issue((kc + 1) * 64);
            __syncthreads();

            bf16x8 af[2];
#pragma unroll
            for (int ks = 0; ks < 2; ks++) {
                floatx4 x0 = *(const floatx4*)&Xd[m * 64 + ((ks * 8 + quad * 2 + 0) ^ (m & 15)) * 4];
                floatx4 x1 = *(const floatx4*)&Xd[m * 64 + ((ks * 8 + quad * 2 + 1) ^ (m & 15)) * 4];
#pragma unroll
                for (int j = 0; j < 4; j++) {
                    af[ks][j]     = (short)f2bf(x0[j]);
                    af[ks][j + 4] = (short)f2bf(x1[j]);
                }
            }
#pragma unroll
            for (int i = 0; i < 6; i++) {
                const int nrow = (cg * 6 + i) * 16 + l16;
#pragma unroll
                for (int ks = 0; ks < 2; ks++) {
                    const int c = ks * 4 + quad;
                    bf16x8 bfrag = *(const bf16x8*)&Wd[nrow * 64 + (c ^ (nrow & 7)) * 8];
                    acc[i] = __builtin_amdgcn_mfma_f32_16x16x32_bf16(af[ks], bfrag, acc[i], 0, 0, 0);
                }
            }
        }
#pragma unroll
        for (int i = 0; i < 6; i++) {
            const int nt = cg * 6 + i;
            const int mat = nt >> 2;
            const int col = (nt & 3) * 16 + l16;
#pragma unroll
            for (int r = 0; r < 4; r++) {
                const int orow = row0 + strip * 16 + quad * 4 + r;
                float v = acc[i][r];
                if (mat == 0) {
                    qb[(size_t)orow * 64 + col] = f2bf(v * QSCALE);
                } else if (mat == 1) {
                    kb[(size_t)orow * 64 + col] = f2bf(v);
                } else {
                    int b = orow >> 12, sq = orow & 4095;
                    vb[((size_t)b * 64 + col) * SEQ + sq] = f2bf(v);
                }
            }
        }
    }
    gbar(cnt + 1, tid);

    // ================= phase 2: attention, work-stealing ====================
    // items: (qt in 31..0 heavy-first, batch, s in 0..7); Q-tile 128 rows =
    // 8 waves x 16; k-range [T*s/8, T*(s+1)/8) of T=2qt+2 64-key tiles.
    {
        unsigned short* K0 = (unsigned short*)smem;              // 8 KB
        unsigned short* K1 = (unsigned short*)(smem + 8192);
        unsigned short* V0 = (unsigned short*)(smem + 16384);
        unsigned short* V1 = (unsigned short*)(smem + 24576);
        unsigned short* Pb = (unsigned short*)(smem + 32768);    // 8 x 16x72
        int* item_s = (int*)(smem + 51200);
        unsigned short* P = Pb + wave * (16 * 72);

        const int ku = tid, kr = ku >> 3, kc_ = (ku & 7) ^ (kr & 7);
        const int vu = tid, vd = vu >> 3, vc = (vu & 7) ^ (vd & 7);

        for (;;) {
            __syncthreads();                       // protect item_s + LDS reuse
            if (tid == 0) *item_s = (int)atomicAdd(cnt + 3, 1u);
            __syncthreads();
            const int it = *item_s;
            if (it >= NITEMS) break;
            const int qt = 31 - (it >> 5);
            const int batch = (it >> 3) & 3;
            const int s = it & 7;
            const int T = 2 * qt + 2;
            const int lo = (T * s) >> 3, hi = (T * (s + 1)) >> 3;
            if (lo == hi) continue;

            const int q0 = qt * 128;
            const unsigned short* kbase = kb + (size_t)batch * SEQ * 64;
            const unsigned short* vbase = vb + (size_t)batch * 64 * SEQ;
            const unsigned short* qr = qb + (size_t)(batch * SEQ + q0 + wave * 16 + l16) * 64;
            bf16x8 qa0 = *(const bf16x8*)(qr + quad * 8);
            bf16x8 qa1 = *(const bf16x8*)(qr + 32 + quad * 8);

            floatx4 o[4];
#pragma unroll
            for (int i = 0; i < 4; i++) o[i] = (floatx4){0.f, 0.f, 0.f, 0.f};
            float lsum = 0.f;

            floatx4 kpre, vpre;
            auto issue = [&](int k0) {
                kpre = *(const floatx4*)(kbase + (size_t)(k0 + kr) * 64 + kc_ * 8);
                vpre = *(const floatx4*)(vbase + (size_t)vd * SEQ + k0 + vc * 8);
            };

            issue(lo * 64);
            for (int kt = lo; kt < hi; kt++) {
                unsigned short* Kd = (kt & 1) ? K1 : K0;
                unsigned short* Vd = (kt & 1) ? V1 : V0;
                *(floatx4*)&Kd[ku * 8] = kpre;
                *(floatx4*)&Vd[vu * 8] = vpre;
                if (kt + 1 < hi) issue((kt + 1) * 64);
                __syncthreads();

                const int k0 = kt * 64;
                floatx4 sc[4];
#pragma unroll
                for (int nt = 0; nt < 4; nt++) {
                    sc[nt] = (floatx4){0.f, 0.f, 0.f, 0.f};
                    const int key = nt * 16 + l16;
#pragma unroll
                    for (int ks = 0; ks < 2; ks++) {
                        const int c = ks * 4 + quad;
                        bf16x8 bk = *(const bf16x8*)&Kd[key * 64 + (c ^ (key & 7)) * 8];
                        sc[nt] = __builtin_amdgcn_mfma_f32_16x16x32_bf16(
                            ks == 0 ? qa0 : qa1, bk, sc[nt], 0, 0, 0);
                    }
                }
                if (k0 + 63 > q0 + wave * 16) {   // causal mask
#pragma unroll
                    for (int nt = 0; nt < 4; nt++) {
                        const int col = k0 + nt * 16 + l16;
#pragma unroll
                        for (int r = 0; r < 4; r++) {
                            const int rowg = q0 + wave * 16 + quad * 4 + r;
                            if (col > rowg) sc[nt][r] = -1e30f;
                        }
                    }
                }
#pragma unroll
                for (int nt = 0; nt < 4; nt++) {
                    float v0 = EXP2(sc[nt][0]), v1 = EXP2(sc[nt][1]);
                    float v2 = EXP2(sc[nt][2]), v3 = EXP2(sc[nt][3]);
                    // 4x4 transpose in 4-lane groups via DPP (VALU pipe)
                    float t0 = dpp_xor2(v0), t1 = dpp_xor2(v1), t2 = dpp_xor2(v2), t3 = dpp_xor2(v3);
                    if (lane & 2) { v0 = t2; v1 = t3; } else { v2 = t0; v3 = t1; }
                    t0 = dpp_xor1(v0); t1 = dpp_xor1(v1); t2 = dpp_xor1(v2); t3 = dpp_xor1(v3);
                    if (lane & 1) { v0 = t1; v2 = t3; } else { v1 = t0; v3 = t2; }
                    unsigned int u0 = fasu(v0) & 0xffff0000u, u1 = fasu(v1) & 0xffff0000u;
                    unsigned int u2 = fasu(v2) & 0xffff0000u, u3 = fasu(v3) & 0xffff0000u;
                    lsum += (uasf(u0) + uasf(u1)) + (uasf(u2) + uasf(u3));
                    uint2 w;
                    w.x = (u0 >> 16) | u1;
                    w.y = (u2 >> 16) | u3;
                    const int prow = quad * 4 + (lane & 3);
                    const int pcol = nt * 16 + (l16 >> 2) * 4;
                    *(uint2*)&P[prow * 72 + pcol] = w;
                }
#pragma unroll
                for (int ks = 0; ks < 2; ks++) {
                    bf16x8 pa = *(const bf16x8*)&P[l16 * 72 + ks * 32 + quad * 8];
#pragma unroll
                    for (int nt = 0; nt < 4; nt++) {
                        const int d = nt * 16 + l16;
                        bf16x8 bv = *(const bf16x8*)&Vd[d * 64 + ((ks * 4 + quad) ^ (d & 7)) * 8];
                        o[nt] = __builtin_amdgcn_mfma_f32_16x16x32_bf16(pa, bv, o[nt], 0, 0, 0);
                    }
                }
            }

            // epilogue: un-normalized bf16 partial + row sums, slot s
            unsigned short* ob = opart + (size_t)s * (4 * SEQ * 64)
                               + (size_t)(batch * SEQ + q0 + wave * 16) * 64;
            float* lb = lpart + (size_t)s * (4 * SEQ) + (batch * SEQ + q0 + wave * 16);
            float l = lsum;
            l += __shfl_xor(l, 4);
            l += __shfl_xor(l, 8);
#pragma unroll
            for (int nt = 0; nt < 4; nt++)
#pragma unroll
                for (int r = 0; r < 4; r++)
                    ob[(quad * 4 + r) * 64 + nt * 16 + l16] = f2bf(o[nt][r]);
            if ((l16 >> 2) == 0) lb[quad * 4 + (lane & 3)] = l;
        }
    }
    gbar(cnt + 2, tid);

    // ================= phase 3: merge valid split slots =====================
    for (int u = bid * 512 + tid; u < 262144; u += 131072) {
        const int row = u >> 4, c4 = u & 15;
        const int qt = (row & 4095) >> 7;
        const int T = 2 * qt + 2;
        float l = 0.f;
        floatx4 acc = (floatx4){0.f, 0.f, 0.f, 0.f};
#pragma unroll
        for (int s = 0; s < 8; s++) {
            const int lo = (T * s) >> 3, hi = (T * (s + 1)) >> 3;
            if (lo < hi) {
                l += lpart[s * (4 * SEQ) + row];
                ushortx4 v = *(const ushortx4*)(opart + (size_t)s * (4 * SEQ * 64)
                                                + (size_t)row * 64 + c4 * 4);
#pragma unroll
                for (int j = 0; j < 4; j++) acc[j] += bf2f(v[j]);
            }
        }
        acc *= (1.f / l);
        *(floatx4*)(out + (size_t)row * 64 + c4 * 4) = acc;
    }
}

extern "C" void kernel_launch(void* const* d_in, const int* in_sizes, int n_in,
                              void* d_out, int out_size, void* d_ws, size_t ws_size,
                              hipStream_t stream) {
    const float* X  = (const float*)d_in[0];
    const float* Wq = (const float*)d_in[1];
    const float* Wk = (const float*)d_in[2];
    const float* Wv = (const float*)d_in[3];
    float* out = (float*)d_out;
    char* ws = (char*)d_ws;
    unsigned short* WT    = (unsigned short*)(ws + 0);         // 384 KB
    unsigned short* qb    = (unsigned short*)(ws + 393216);    // 2 MB
    unsigned short* kb    = (unsigned short*)(ws + 2490368);   // 2 MB
    unsigned short* vb    = (unsigned short*)(ws + 4587520);   // 2 MB
    unsigned short* opart = (unsigned short*)(ws + 6684672);   // 16 MB (8 slots bf16)
    float*          lpart = (float*)(ws + 23461888);           // 512 KB
    unsigned int*   cnt   = (unsigned int*)(ws + 23986176);    // 16 B

    hipMemsetAsync(cnt, 0, 16, stream);   // 3 barrier counters + work counter
    hipLaunchKernelGGL(mega, dim3(NBLK), dim3(512), 0, stream,
                       X, Wq, Wk, Wv, WT, qb, kb, vb, opart, lpart, cnt, out);
}

// Round 8
// 135.008 us; speedup vs baseline: 1.9354x; 1.9354x over previous
//
#include <hip/hip_runtime.h>
#include <stdint.h>

#define SEQ   4096
#define DIN   1024

typedef __attribute__((ext_vector_type(8))) short bf16x8;
typedef __attribute__((ext_vector_type(4))) float floatx4;
typedef __attribute__((ext_vector_type(4))) unsigned short ushortx4;

#if __has_builtin(__builtin_amdgcn_exp2f)
#define EXP2(x) __builtin_amdgcn_exp2f(x)
#else
#define EXP2(x) exp2f(x)
#endif

__device__ __forceinline__ unsigned short f2bf(float f) {
    union { float f; unsigned int u; } v; v.f = f;
    unsigned int u = v.u + 0x7fffu + ((v.u >> 16) & 1u);
    return (unsigned short)(u >> 16);
}
__device__ __forceinline__ float bf2f(unsigned short h) {
    union { unsigned int u; float f; } v; v.u = ((unsigned int)h) << 16;
    return v.f;
}
__device__ __forceinline__ float uasf(unsigned int u) {
    union { unsigned int u; float f; } v; v.u = u; return v.f;
}
__device__ __forceinline__ unsigned int fasu(float f) {
    union { float f; unsigned int u; } v; v.f = f; return v.u;
}
__device__ __forceinline__ float dpp_xor1(float x) {   // quad_perm [1,0,3,2]
    return uasf((unsigned)__builtin_amdgcn_mov_dpp((int)fasu(x), 0xB1, 0xF, 0xF, true));
}
__device__ __forceinline__ float dpp_xor2(float x) {   // quad_perm [2,3,0,1]
    return uasf((unsigned)__builtin_amdgcn_mov_dpp((int)fasu(x), 0x4E, 0xF, 0xF, true));
}

// ---------------- prep: WT[mat*64+n][k] = bf16(W[k][n]) ----------------
__global__ void wt_prep(const float* __restrict__ Wq, const float* __restrict__ Wk,
                        const float* __restrict__ Wv, unsigned short* __restrict__ WT) {
    int idx = blockIdx.x * 256 + threadIdx.x;      // writes coalesced
    int k   = idx & 1023;
    int n   = (idx >> 10) & 63;
    int mat = idx >> 16;
    const float* W = (mat == 0) ? Wq : ((mat == 1) ? Wk : Wv);
    WT[idx] = f2bf(W[k * 64 + n]);
}

// ---------------- projection: q,k,v = x @ W{q,k,v} ----------------
// grid 256, block 512 (8 waves = 4 row-strips x 2 col-groups). BM=64:
// W re-stage traffic 96 MB + X 64 MB; ~11 TB/s per-CU-return ceiling
// => ~15 us floor. Double-buffered reg-prefetch, one barrier per chunk.
#define QSCALE 0.18033688011112042f
__launch_bounds__(512, 2)
__global__ void proj_qkv(const float* __restrict__ X, const unsigned short* __restrict__ WT,
                         unsigned short* __restrict__ qb, unsigned short* __restrict__ kb,
                         unsigned short* __restrict__ vb) {
    __shared__ __align__(16) float          X0[64 * 64], X1[64 * 64];     // 16 KB each
    __shared__ __align__(16) unsigned short W0[192 * 64], W1[192 * 64];   // 24 KB each
    const int tid = threadIdx.x;
    const int wave = tid >> 6, lane = tid & 63;
    const int quad = lane >> 4, l16 = lane & 15;
    const int strip = wave >> 1;            // rows strip*16..+16
    const int cg = wave & 1;                // cols cg*96..+96
    const int row0 = blockIdx.x * 64;
    const int m = strip * 16 + l16;

    floatx4 acc[6];
#pragma unroll
    for (int i = 0; i < 6; i++) acc[i] = (floatx4){0.f, 0.f, 0.f, 0.f};

    int xu[2], xr[2], xc[2], wu[3], wr[3], wc[3];
#pragma unroll
    for (int i = 0; i < 2; i++) {
        xu[i] = i * 512 + tid; xr[i] = xu[i] >> 4; xc[i] = (xu[i] & 15) ^ (xr[i] & 15);
    }
#pragma unroll
    for (int i = 0; i < 3; i++) {
        wu[i] = i * 512 + tid; wr[i] = wu[i] >> 3; wc[i] = (wu[i] & 7) ^ (wr[i] & 7);
    }
    floatx4 xpre[2], wpre[3];
    auto issue = [&](int k0) {
#pragma unroll
        for (int i = 0; i < 2; i++)
            xpre[i] = *(const floatx4*)(X + (size_t)(row0 + xr[i]) * DIN + k0 + xc[i] * 4);
#pragma unroll
        for (int i = 0; i < 3; i++)
            wpre[i] = *(const floatx4*)(WT + (size_t)wr[i] * 1024 + k0 + wc[i] * 8);
    };

    issue(0);
    for (int kc = 0; kc < 16; kc++) {
        float*          Xd = (kc & 1) ? X1 : X0;
        unsigned short* Wd = (kc & 1) ? W1 : W0;
#pragma unroll
        for (int i = 0; i < 2; i++) *(floatx4*)&Xd[xu[i] * 4] = xpre[i];
#pragma unroll
        for (int i = 0; i < 3; i++) *(floatx4*)&Wd[wu[i] * 8] = wpre[i];
        if (kc < 15) issue((kc + 1) * 64);   // in flight across the barrier
        __syncthreads();

        bf16x8 af[2];
#pragma unroll
        for (int ks = 0; ks < 2; ks++) {
            floatx4 x0 = *(const floatx4*)&Xd[m * 64 + ((ks * 8 + quad * 2 + 0) ^ (m & 15)) * 4];
            floatx4 x1 = *(const floatx4*)&Xd[m * 64 + ((ks * 8 + quad * 2 + 1) ^ (m & 15)) * 4];
#pragma unroll
            for (int j = 0; j < 4; j++) {
                af[ks][j]     = (short)f2bf(x0[j]);
                af[ks][j + 4] = (short)f2bf(x1[j]);
            }
        }
#pragma unroll
        for (int i = 0; i < 6; i++) {
            const int nrow = (cg * 6 + i) * 16 + l16;
#pragma unroll
            for (int ks = 0; ks < 2; ks++) {
                const int c = ks * 4 + quad;
                bf16x8 bfrag = *(const bf16x8*)&Wd[nrow * 64 + (c ^ (nrow & 7)) * 8];
                acc[i] = __builtin_amdgcn_mfma_f32_16x16x32_bf16(af[ks], bfrag, acc[i], 0, 0, 0);
            }
        }
    }
#pragma unroll
    for (int i = 0; i < 6; i++) {
        const int nt = cg * 6 + i;
        const int mat = nt >> 2;
        const int col = (nt & 3) * 16 + l16;
#pragma unroll
        for (int r = 0; r < 4; r++) {
            const int orow = row0 + strip * 16 + quad * 4 + r;
            float v = acc[i][r];
            if (mat == 0) {
                qb[(size_t)orow * 64 + col] = f2bf(v * QSCALE);
            } else if (mat == 1) {
                kb[(size_t)orow * 64 + col] = f2bf(v);
            } else {  // v stored transposed: vb[b][d][s]
                int b = orow >> 12, sq = orow & 4095;
                vb[((size_t)b * 64 + col) * SEQ + sq] = f2bf(v);
            }
        }
    }
}

// ---------------- flash attention, causal, fixed-base softmax ----------------
// grid 1024 = 64 work-ranks x 4 batches x 4 K-splits, heavy blocks first.
// Block 256 = 4 waves x 16 q-rows (Q-tile 64). Single-buffer K/V (16 KB) +
// P strips (9 KB) = 25.6 KB -> 4+ blocks/CU: inter-block overlap hides the
// barrier drain (m114). Reg-prefetch one tile ahead. Empty splits write
// zeros so merge is unconditional.
__launch_bounds__(256, 4)
__global__ void attn(const unsigned short* __restrict__ qb, const unsigned short* __restrict__ kb,
                     const unsigned short* __restrict__ vb, unsigned short* __restrict__ opart,
                     float* __restrict__ lpart) {
    __shared__ __align__(16) unsigned short Kl[64 * 64];      // 8 KB [key][d], swizzled
    __shared__ __align__(16) unsigned short Vl[64 * 64];      // 8 KB [d][key], swizzled
    __shared__ __align__(16) unsigned short Pl[4][16 * 72];   // 9 KB per-wave P strips

    const int bid = blockIdx.x;
    const int qt = 63 - (bid >> 4);          // heavy (large qt) dispatched first
    const int batch = (bid >> 2) & 3;
    const int s = bid & 3;
    const int q0 = qt * 64;
    const int T = qt + 1;                    // 64-key tiles in causal range
    const int lo = (T * s) >> 2, hi = (T * (s + 1)) >> 2;

    const int tid = threadIdx.x;
    const int wave = tid >> 6, lane = tid & 63;
    const int quad = lane >> 4, l16 = lane & 15;

    const unsigned short* qr = qb + (size_t)(batch * SEQ + q0 + wave * 16 + l16) * 64;
    bf16x8 qa0 = *(const bf16x8*)(qr + quad * 8);
    bf16x8 qa1 = *(const bf16x8*)(qr + 32 + quad * 8);

    floatx4 o[4];
#pragma unroll
    for (int i = 0; i < 4; i++) o[i] = (floatx4){0.f, 0.f, 0.f, 0.f};
    float lsum = 0.f;

    const unsigned short* kbase = kb + (size_t)batch * SEQ * 64;
    const unsigned short* vbase = vb + (size_t)batch * 64 * SEQ;
    unsigned short* P = &Pl[wave][0];

    // staging: K 512 16B-units + V 512 units, 2+2 per thread
    int ku[2], kr[2], kc_[2], vu[2], vd[2], vc[2];
#pragma unroll
    for (int i = 0; i < 2; i++) {
        ku[i] = i * 256 + tid; kr[i] = ku[i] >> 3; kc_[i] = (ku[i] & 7) ^ (kr[i] & 7);
        vu[i] = i * 256 + tid; vd[i] = vu[i] >> 3; vc[i] = (vu[i] & 7) ^ (vd[i] & 7);
    }
    floatx4 kpre[2], vpre[2];
    auto issue = [&](int k0) {
#pragma unroll
        for (int i = 0; i < 2; i++)
            kpre[i] = *(const floatx4*)(kbase + (size_t)(k0 + kr[i]) * 64 + kc_[i] * 8);
#pragma unroll
        for (int i = 0; i < 2; i++)
            vpre[i] = *(const floatx4*)(vbase + (size_t)vd[i] * SEQ + k0 + vc[i] * 8);
    };

    if (lo < hi) issue(lo * 64);
    for (int kt = lo; kt < hi; kt++) {
        __syncthreads();                     // readers of tile kt-1 done
#pragma unroll
        for (int i = 0; i < 2; i++) *(floatx4*)&Kl[ku[i] * 8] = kpre[i];
#pragma unroll
        for (int i = 0; i < 2; i++) *(floatx4*)&Vl[vu[i] * 8] = vpre[i];
        if (kt + 1 < hi) issue((kt + 1) * 64);   // lands during compute below
        __syncthreads();                     // tile kt visible

        const int k0 = kt * 64;
        floatx4 sc[4];
#pragma unroll
        for (int nt = 0; nt < 4; nt++) {
            sc[nt] = (floatx4){0.f, 0.f, 0.f, 0.f};
            const int key = nt * 16 + l16;
#pragma unroll
            for (int ks = 0; ks < 2; ks++) {
                const int c = ks * 4 + quad;
                bf16x8 bk = *(const bf16x8*)&Kl[key * 64 + (c ^ (key & 7)) * 8];
                sc[nt] = __builtin_amdgcn_mfma_f32_16x16x32_bf16(
                    ks == 0 ? qa0 : qa1, bk, sc[nt], 0, 0, 0);
            }
        }
        if (kt == T - 1) {                   // diagonal tile: causal mask
#pragma unroll
            for (int nt = 0; nt < 4; nt++) {
                const int col = k0 + nt * 16 + l16;
#pragma unroll
                for (int r = 0; r < 4; r++) {
                    const int rowg = q0 + wave * 16 + quad * 4 + r;
                    if (col > rowg) sc[nt][r] = -1e30f;
                }
            }
        }
#pragma unroll
        for (int nt = 0; nt < 4; nt++) {
            // p = exp2(s) (fixed-base softmax, log2 domain, q pre-scaled)
            float v0 = EXP2(sc[nt][0]), v1 = EXP2(sc[nt][1]);
            float v2 = EXP2(sc[nt][2]), v3 = EXP2(sc[nt][3]);
            // 4x4 transpose in 4-lane groups via DPP (VALU pipe)
            float t0 = dpp_xor2(v0), t1 = dpp_xor2(v1), t2 = dpp_xor2(v2), t3 = dpp_xor2(v3);
            if (lane & 2) { v0 = t2; v1 = t3; } else { v2 = t0; v3 = t1; }
            t0 = dpp_xor1(v0); t1 = dpp_xor1(v1); t2 = dpp_xor1(v2); t3 = dpp_xor1(v3);
            if (lane & 1) { v0 = t1; v2 = t3; } else { v1 = t0; v3 = t2; }
            // truncate to bf16; lsum accumulates the SAME truncated values
            unsigned int u0 = fasu(v0) & 0xffff0000u, u1 = fasu(v1) & 0xffff0000u;
            unsigned int u2 = fasu(v2) & 0xffff0000u, u3 = fasu(v3) & 0xffff0000u;
            lsum += (uasf(u0) + uasf(u1)) + (uasf(u2) + uasf(u3));
            uint2 w;
            w.x = (u0 >> 16) | u1;
            w.y = (u2 >> 16) | u3;
            const int prow = quad * 4 + (lane & 3);
            const int pcol = nt * 16 + (l16 >> 2) * 4;
            *(uint2*)&P[prow * 72 + pcol] = w;
        }
        // PV: A = P (wave-private LDS strip), B = V^T
#pragma unroll
        for (int ks = 0; ks < 2; ks++) {
            bf16x8 pa = *(const bf16x8*)&P[l16 * 72 + ks * 32 + quad * 8];
#pragma unroll
            for (int nt = 0; nt < 4; nt++) {
                const int d = nt * 16 + l16;
                bf16x8 bv = *(const bf16x8*)&Vl[d * 64 + ((ks * 4 + quad) ^ (d & 7)) * 8];
                o[nt] = __builtin_amdgcn_mfma_f32_16x16x32_bf16(pa, bv, o[nt], 0, 0, 0);
            }
        }
    }

    // epilogue: un-normalized bf16 partial + row sums (zeros if empty split)
    unsigned short* ob = opart + (size_t)s * (4 * SEQ * 64)
                       + (size_t)(batch * SEQ + q0 + wave * 16) * 64;
    float* lb = lpart + (size_t)s * (4 * SEQ) + (batch * SEQ + q0 + wave * 16);
    float l = lsum;
    l += __shfl_xor(l, 4);
    l += __shfl_xor(l, 8);
#pragma unroll
    for (int nt = 0; nt < 4; nt++)
#pragma unroll
        for (int r = 0; r < 4; r++)
            ob[(quad * 4 + r) * 64 + nt * 16 + l16] = f2bf(o[nt][r]);
    if ((l16 >> 2) == 0) lb[quad * 4 + (lane & 3)] = l;
}

// ---------------- merge the four split-K partials ----------------
__global__ void merge(const unsigned short* __restrict__ opart, const float* __restrict__ lpart,
                      float* __restrict__ out) {
    int idx = blockIdx.x * 256 + threadIdx.x;   // [0, 262144): 4-col units
    int row = idx >> 4, c4 = idx & 15;
    float l = lpart[row] + lpart[4 * SEQ + row] + lpart[8 * SEQ + row] + lpart[12 * SEQ + row];
    float inv = 1.f / l;
    floatx4 acc = (floatx4){0.f, 0.f, 0.f, 0.f};
#pragma unroll
    for (int s = 0; s < 4; s++) {
        ushortx4 u = *(const ushortx4*)(opart + (size_t)s * (4 * SEQ * 64)
                                        + (size_t)row * 64 + c4 * 4);
#pragma unroll
        for (int j = 0; j < 4; j++) acc[j] += bf2f(u[j]);
    }
    acc *= inv;
    *(floatx4*)(out + (size_t)row * 64 + c4 * 4) = acc;
}

extern "C" void kernel_launch(void* const* d_in, const int* in_sizes, int n_in,
                              void* d_out, int out_size, void* d_ws, size_t ws_size,
                              hipStream_t stream) {
    const float* X  = (const float*)d_in[0];
    const float* Wq = (const float*)d_in[1];
    const float* Wk = (const float*)d_in[2];
    const float* Wv = (const float*)d_in[3];
    float* out = (float*)d_out;
    char* ws = (char*)d_ws;
    unsigned short* WT    = (unsigned short*)(ws + 0);         // 384 KB
    unsigned short* qb    = (unsigned short*)(ws + 393216);    // 2 MB
    unsigned short* kb    = (unsigned short*)(ws + 2490368);   // 2 MB
    unsigned short* vb    = (unsigned short*)(ws + 4587520);   // 2 MB
    unsigned short* opart = (unsigned short*)(ws + 6684672);   // 8 MB (4 slots, bf16)
    float*          lpart = (float*)(ws + 15073280);           // 256 KB

    hipLaunchKernelGGL(wt_prep,  dim3(768),  dim3(256), 0, stream, Wq, Wk, Wv, WT);
    hipLaunchKernelGGL(proj_qkv, dim3(256),  dim3(512), 0, stream, X, WT, qb, kb, vb);
    hipLaunchKernelGGL(attn,     dim3(1024), dim3(256), 0, stream, qb, kb, vb, opart, lpart);
    hipLaunchKernelGGL(merge,    dim3(1024), dim3(256), 0, stream, opart, lpart, out);
}